// Round 1
// 942.280 us; speedup vs baseline: 1.0379x; 1.0379x over previous
//
#include <hip/hip_runtime.h>

// NBVLoss: weighted BCE reduction over 4096x32768 fp32.
//   total = 10 * sum_{t==1} min(-log(p),100) + 1 * sum_{t==0} min(-log(1-p),100)
// Memory-bound: 1.074 GB read -> ~170-195us floor at 5.5-6.3 TB/s.
//
// v2 changes vs atomic version:
//  - Two-phase reduction: per-block partials into d_ws, then 1-block reduce
//    kernel writes out directly. Removes 4096 same-address device-scope
//    fp32 atomics (serialized burst tail across 8 non-coherent XCDs) and
//    the hipMemsetAsync dispatch.
//  - grid 2048 (all blocks co-resident: 8 blocks/CU x 256 CUs), grid-stride.
//  - Non-temporal loads: pure streaming, zero reuse -> skip cache fill.

#define LAMBDA_FOR1 10.0f

typedef float f32x4 __attribute__((ext_vector_type(4)));

__device__ __forceinline__ float bce_term(float p, float t) {
    // t is exactly 0.0f or 1.0f per the reference's bernoulli->float input.
    bool is_one = (t != 0.0f);
    float x = is_one ? p : (1.0f - p);          // 1-p exact for p>=0.5 (Sterbenz)
    float l = fminf(-__logf(x), 100.0f);        // -log clamped at 100 (x==0 -> inf ok)
    return is_one ? (LAMBDA_FOR1 * l) : l;
}

__device__ __forceinline__ float block_reduce_256(float acc) {
    // Wave (64-lane) shuffle reduction, then 4-wave LDS combine.
#pragma unroll
    for (int off = 32; off > 0; off >>= 1)
        acc += __shfl_down(acc, off, 64);
    __shared__ float wave_sum[4];   // 256 threads = 4 waves
    const int lane = threadIdx.x & 63;
    const int wid  = threadIdx.x >> 6;
    if (lane == 0) wave_sum[wid] = acc;
    __syncthreads();
    return wave_sum[0] + wave_sum[1] + wave_sum[2] + wave_sum[3];
}

__global__ __launch_bounds__(256) void nbv_partial_kernel(
        const f32x4* __restrict__ pred4,
        const f32x4* __restrict__ tgt4,
        float* __restrict__ partials,
        int n4, int tail_base, int tail_count) {
    float acc = 0.0f;
    const int stride = gridDim.x * blockDim.x;
    for (int i = blockIdx.x * blockDim.x + threadIdx.x; i < n4; i += stride) {
        f32x4 p = __builtin_nontemporal_load(pred4 + i);
        f32x4 t = __builtin_nontemporal_load(tgt4 + i);
        acc += bce_term(p.x, t.x);
        acc += bce_term(p.y, t.y);
        acc += bce_term(p.z, t.z);
        acc += bce_term(p.w, t.w);
    }
    // Scalar tail (n not divisible by 4) — handled by block 0 only.
    if (blockIdx.x == 0 && (int)threadIdx.x < tail_count) {
        const float* pred = (const float*)pred4;
        const float* tgt  = (const float*)tgt4;
        int i = tail_base + threadIdx.x;
        acc += bce_term(pred[i], tgt[i]);
    }

    float s = block_reduce_256(acc);
    if (threadIdx.x == 0)
        partials[blockIdx.x] = s;   // no atomics; one coalesced-enough store/block
}

__global__ __launch_bounds__(256) void nbv_reduce_kernel(
        const float* __restrict__ partials,
        float* __restrict__ out,
        int n) {
    float acc = 0.0f;
    for (int i = threadIdx.x; i < n; i += 256)
        acc += partials[i];
    float s = block_reduce_256(acc);
    if (threadIdx.x == 0)
        out[0] = s;                 // plain store; d_out poison is overwritten
}

extern "C" void kernel_launch(void* const* d_in, const int* in_sizes, int n_in,
                              void* d_out, int out_size, void* d_ws, size_t ws_size,
                              hipStream_t stream) {
    const float* pred = (const float*)d_in[0];   // predictions, fp32
    const float* tgt  = (const float*)d_in[1];   // target, fp32 (0.0 or 1.0)
    float* out = (float*)d_out;                  // scalar fp32 result
    float* partials = (float*)d_ws;              // per-block partial sums

    const int n  = in_sizes[0];                  // 134,217,728 (fits in int32)
    const int n4 = n >> 2;
    const int tail_base  = n4 << 2;
    const int tail_count = n - tail_base;

    const int block = 256;
    const int grid  = 2048;                      // 8 blocks/CU, all co-resident

    nbv_partial_kernel<<<grid, block, 0, stream>>>(
        (const f32x4*)pred, (const f32x4*)tgt, partials, n4, tail_base, tail_count);
    nbv_reduce_kernel<<<1, block, 0, stream>>>(partials, out, grid);
}

// Round 2
// 934.706 us; speedup vs baseline: 1.0463x; 1.0081x over previous
//
#include <hip/hip_runtime.h>

// NBVLoss: weighted BCE reduction over 4096x32768 fp32.
//   total = 10 * sum_{t==1} min(-log(p),100) + 1 * sum_{t==0} min(-log(1-p),100)
// Memory-bound: 1.074 GB read -> ~170-195us floor at 5.5-6.3 TB/s.
//
// v3 changes vs v2:
//  - 4x unrolled grid-stride loop: 8 independent 16B nontemporal loads in
//    flight per wave (was 2) -> hide ~900cy HBM latency per-wave instead of
//    relying purely on TLP.
//  - Dual accumulators to break the serial v_add_f32 dependency chain.
//  - VGPR stays < 64 so occupancy remains 8 waves/SIMD (32/CU).

#define LAMBDA_FOR1 10.0f

typedef float f32x4 __attribute__((ext_vector_type(4)));

__device__ __forceinline__ float bce_term(float p, float t) {
    // t is exactly 0.0f or 1.0f per the reference's bernoulli->float input.
    bool is_one = (t != 0.0f);
    float x = is_one ? p : (1.0f - p);          // 1-p exact for p>=0.5 (Sterbenz)
    float l = fminf(-__logf(x), 100.0f);        // -log clamped at 100 (x==0 -> inf ok)
    return is_one ? (LAMBDA_FOR1 * l) : l;
}

__device__ __forceinline__ float bce4(f32x4 p, f32x4 t) {
    return (bce_term(p.x, t.x) + bce_term(p.y, t.y)) +
           (bce_term(p.z, t.z) + bce_term(p.w, t.w));
}

__device__ __forceinline__ float block_reduce_256(float acc) {
    // Wave (64-lane) shuffle reduction, then 4-wave LDS combine.
#pragma unroll
    for (int off = 32; off > 0; off >>= 1)
        acc += __shfl_down(acc, off, 64);
    __shared__ float wave_sum[4];   // 256 threads = 4 waves
    const int lane = threadIdx.x & 63;
    const int wid  = threadIdx.x >> 6;
    if (lane == 0) wave_sum[wid] = acc;
    __syncthreads();
    return wave_sum[0] + wave_sum[1] + wave_sum[2] + wave_sum[3];
}

__global__ __launch_bounds__(256) void nbv_partial_kernel(
        const f32x4* __restrict__ pred4,
        const f32x4* __restrict__ tgt4,
        float* __restrict__ partials,
        int n4, int tail_base, int tail_count) {
    float acc0 = 0.0f, acc1 = 0.0f;
    const int stride = gridDim.x * blockDim.x;
    int i = blockIdx.x * blockDim.x + threadIdx.x;

    // 4x unrolled grid-stride: 8 independent loads in flight per wave.
    // (n4 = 2048*256*64 exactly -> this loop does all the work; remainder
    //  loop below keeps correctness for general n.)
    for (; i + 3 * stride < n4; i += 4 * stride) {
        f32x4 p0 = __builtin_nontemporal_load(pred4 + i);
        f32x4 t0 = __builtin_nontemporal_load(tgt4 + i);
        f32x4 p1 = __builtin_nontemporal_load(pred4 + i + stride);
        f32x4 t1 = __builtin_nontemporal_load(tgt4 + i + stride);
        f32x4 p2 = __builtin_nontemporal_load(pred4 + i + 2 * stride);
        f32x4 t2 = __builtin_nontemporal_load(tgt4 + i + 2 * stride);
        f32x4 p3 = __builtin_nontemporal_load(pred4 + i + 3 * stride);
        f32x4 t3 = __builtin_nontemporal_load(tgt4 + i + 3 * stride);
        acc0 += bce4(p0, t0);
        acc1 += bce4(p1, t1);
        acc0 += bce4(p2, t2);
        acc1 += bce4(p3, t3);
    }
    for (; i < n4; i += stride) {
        f32x4 p = __builtin_nontemporal_load(pred4 + i);
        f32x4 t = __builtin_nontemporal_load(tgt4 + i);
        acc0 += bce4(p, t);
    }
    float acc = acc0 + acc1;

    // Scalar tail (n not divisible by 4) — handled by block 0 only.
    if (blockIdx.x == 0 && (int)threadIdx.x < tail_count) {
        const float* pred = (const float*)pred4;
        const float* tgt  = (const float*)tgt4;
        int j = tail_base + threadIdx.x;
        acc += bce_term(pred[j], tgt[j]);
    }

    float s = block_reduce_256(acc);
    if (threadIdx.x == 0)
        partials[blockIdx.x] = s;   // no atomics; one tiny store per block
}

__global__ __launch_bounds__(256) void nbv_reduce_kernel(
        const float* __restrict__ partials,
        float* __restrict__ out,
        int n) {
    float acc = 0.0f;
    for (int i = threadIdx.x; i < n; i += 256)
        acc += partials[i];
    float s = block_reduce_256(acc);
    if (threadIdx.x == 0)
        out[0] = s;                 // plain store; d_out poison is overwritten
}

extern "C" void kernel_launch(void* const* d_in, const int* in_sizes, int n_in,
                              void* d_out, int out_size, void* d_ws, size_t ws_size,
                              hipStream_t stream) {
    const float* pred = (const float*)d_in[0];   // predictions, fp32
    const float* tgt  = (const float*)d_in[1];   // target, fp32 (0.0 or 1.0)
    float* out = (float*)d_out;                  // scalar fp32 result
    float* partials = (float*)d_ws;              // per-block partial sums

    const int n  = in_sizes[0];                  // 134,217,728 (fits in int32)
    const int n4 = n >> 2;
    const int tail_base  = n4 << 2;
    const int tail_count = n - tail_base;

    const int block = 256;
    const int grid  = 2048;                      // 8 blocks/CU, all co-resident

    nbv_partial_kernel<<<grid, block, 0, stream>>>(
        (const f32x4*)pred, (const f32x4*)tgt, partials, n4, tail_base, tail_count);
    nbv_reduce_kernel<<<1, block, 0, stream>>>(partials, out, grid);
}